// Round 6
// baseline (112.682 us; speedup 1.0000x reference)
//
#include <hip/hip_runtime.h>
#include <math.h>
#include <float.h>

// Problem constants (fixed by setup_inputs):
//   outputs: [8, 512, 12]            fp32
//   targets: [8, 512, 1, 2, 128]     fp32
//   W_dec:   [12, 256]               fp32
//   b_dec:   [256]                   fp32
//   out:     scalar fp32
#define NCOMP 12
#define NS 128
#define NBS 4096   // 8 * 512

// Data-placement swizzle for pack WRITES. Reads are slot-indexed; a sum over
// per-point mins is invariant to bijective relabeling, so no inverse needed.
__device__ __forceinline__ int swz(int p) { return p ^ ((p >> 3) & 7); }

__global__ __launch_bounds__(256)
void p2cp_fused_kernel(const float* __restrict__ outputs,
                       const float* __restrict__ targets,
                       const float* __restrict__ W_dec,
                       const float* __restrict__ b_dec,
                       unsigned int* __restrict__ tickets,  // [0]=global, [16+g*16]=group g
                       unsigned int* __restrict__ partial,  // [NBS] bit-cast floats, RMW-only
                       float* __restrict__ out) {
    const int bsq = blockIdx.x;      // flattened (b, s)
    const int t   = threadIdx.x;     // 0..255

    __shared__ __align__(16) float2 sxy[2 * NS];  // slots 0..127 u, 128..255 v: {x,y}
    __shared__ __align__(16) float  szz[2 * NS];  // |p|^2 per slot
    __shared__ float o[NCOMP];
    __shared__ float red[4];
    __shared__ unsigned int s_role;

    if (t < NCOMP) o[t] = outputs[bsq * NCOMP + t];

    // targets per (b,s): [2][128]
    const float* tb = targets + (size_t)bsq * (2 * NS);
    const float tval = tb[t];
    float vx2 = 0.0f;
    if (t >= NS) vx2 = tb[t - NS];   // x-coord for v-point t-128
    __syncthreads();   // o[] ready

    if (t < NS) {
        // decode BOTH coords of u-point t: x = shapes[t], y = shapes[128+t]
        float x = b_dec[t], y = b_dec[NS + t];
        #pragma unroll
        for (int k = 0; k < NCOMP; ++k) {
            x = fmaf(o[k], W_dec[k * 256 + t], x);
            y = fmaf(o[k], W_dec[k * 256 + NS + t], y);
        }
        const int s = swz(t);
        sxy[s] = make_float2(x, y);
        szz[s] = fmaf(x, x, y * y);
    } else {
        // v-point j = t-128: x = tb[j], y = tb[128+j] = tval
        const int j = t - NS;
        const float x = vx2, y = tval;
        const int s = swz(NS + j);
        sxy[s] = make_float2(x, y);
        szz[s] = fmaf(x, x, y * y);
    }
    __syncthreads();   // points ready

    // Tiling: group = t>>3 owns 8 stored slots [group*8, group*8+8).
    // Groups 0..15 -> u side (min over v slots), 16..31 -> v side.
    // slice = t&7 handles candidate slot-pairs m = slice + 8i (slots 2m, 2m+1).
    const int slice   = t & 7;
    const int group   = t >> 3;
    const int ownBase = group * 8;
    const float* opp_xy = reinterpret_cast<const float*>((ownBase < NS) ? (sxy + NS) : sxy);
    const float* opp_zz = (ownBase < NS) ? (szz + NS) : szz;

    float a[8], b[8], mn[8];
    #pragma unroll
    for (int k = 0; k < 8; ++k) {
        const float2 p = sxy[ownBase + k];
        a[k] = -2.0f * p.x;
        b[k] = -2.0f * p.y;
        mn[k] = FLT_MAX;
    }

    // Gram form: d2(p,q) = |p|^2 + (|q|^2 - 2 px qx - 2 py qy); |p|^2 added at end.
    #pragma unroll 4
    for (int i = 0; i < 8; ++i) {
        const int m = slice + 8 * i;                 // candidate slot-pair index
        const float4 q  = *reinterpret_cast<const float4*>(opp_xy + 4 * m); // {x0,y0,x1,y1}
        const float2 z2 = *reinterpret_cast<const float2*>(opp_zz + 2 * m); // {z0,z1}
        #pragma unroll
        for (int k = 0; k < 8; ++k) {
            const float d0 = fmaf(a[k], q.x, fmaf(b[k], q.y, z2.x));
            const float d1 = fmaf(a[k], q.z, fmaf(b[k], q.w, z2.y));
            mn[k] = fminf(mn[k], fminf(d0, d1));     // v_min3 candidate
        }
    }

    // Combine partial mins across the 8 slices (adjacent lanes, same wave).
    #pragma unroll
    for (int k = 0; k < 8; ++k) {
        mn[k] = fminf(mn[k], __shfl_xor(mn[k], 1));
        mn[k] = fminf(mn[k], __shfl_xor(mn[k], 2));
        mn[k] = fminf(mn[k], __shfl_xor(mn[k], 4));
    }

    // Lane (group, slice) finalizes stored slot ownBase + slice == t.
    float mm = mn[0];
    #pragma unroll
    for (int k = 1; k < 8; ++k) mm = (slice == k) ? mn[k] : mm;
    const float d2 = fmaxf(mm + szz[t], 0.0f);       // own |p|^2 lives at slot t
    float m = sqrtf(d2 + 1e-12f);                    // sqrt monotone: one sqrt after min

    // Block sum across 256 threads.
    #pragma unroll
    for (int off = 32; off > 0; off >>= 1)
        m += __shfl_down(m, off);
    const int lane = t & 63;
    const int wid  = t >> 6;
    if (lane == 0) red[wid] = m;
    __syncthreads();

    // --- deterministic fused finish, RMW-only cross-block data movement ---
    if (t == 0) {
        const float blocksum = red[0] + red[1] + red[2] + red[3];
        // WRITE via atomic exchange: executes at the coherent point (cross-XCD safe).
        __hip_atomic_exchange(&partial[bsq], __float_as_uint(blocksum),
                              __ATOMIC_RELEASE, __HIP_MEMORY_SCOPE_AGENT);
        unsigned int role = 0;
        const int g = bsq >> 6;   // 64 groups of 64 blocks
        const unsigned int gt = __hip_atomic_fetch_add(&tickets[16 + g * 16], 1u,
                                                       __ATOMIC_ACQ_REL, __HIP_MEMORY_SCOPE_AGENT);
        if ((gt & 63u) == 63u) {  // group closer (any initial counter value works)
            const unsigned int ft = __hip_atomic_fetch_add(&tickets[0], 1u,
                                                           __ATOMIC_ACQ_REL, __HIP_MEMORY_SCOPE_AGENT);
            role = ((ft & 63u) == 63u) ? 1u : 0u;   // last closer -> final reducer
        }
        s_role = role;
    }
    __syncthreads();

    if (s_role != 0u) {
        // Final block: READ partials via atomic RMW (fetch_add 0) — cannot be
        // served stale; happens-before chain via the two ticket levels
        // guarantees all 4096 exchanges are ordered before these RMWs.
        float s = 0.0f;
        #pragma unroll
        for (int i = 0; i < 16; ++i) {
            const unsigned int u = __hip_atomic_fetch_add(&partial[t + 256 * i], 0u,
                                                          __ATOMIC_ACQ_REL, __HIP_MEMORY_SCOPE_AGENT);
            s += __uint_as_float(u);
        }
        #pragma unroll
        for (int off = 32; off > 0; off >>= 1)
            s += __shfl_down(s, off);
        if (lane == 0) red[wid] = s;
        __syncthreads();
        if (t == 0) {
            const float total = red[0] + red[1] + red[2] + red[3];
            // per-(b,s): blocksum/256; then mean over 4096 (b,s,art)
            out[0] = total * (1.0f / (256.0f * (float)NBS));
        }
    }
}

extern "C" void kernel_launch(void* const* d_in, const int* in_sizes, int n_in,
                              void* d_out, int out_size, void* d_ws, size_t ws_size,
                              hipStream_t stream) {
    const float* outputs = (const float*)d_in[0];
    const float* targets = (const float*)d_in[1];
    const float* W_dec   = (const float*)d_in[2];
    const float* b_dec   = (const float*)d_in[3];
    float* out = (float*)d_out;

    // ws layout: [0, 4160) ticket counters (uint, 64B-spaced); [8192, 8192+16KB) partials.
    // Counters are never reset: each call adds exactly 64 tickets/counter; exactly one
    // of any 64 consecutive values is ==63 (mod 64) -> works from any initial state.
    // Partials are fully overwritten (atomicExch) before any read each call.
    unsigned int* tickets = (unsigned int*)d_ws;
    unsigned int* partial = (unsigned int*)((char*)d_ws + 8192);

    p2cp_fused_kernel<<<NBS, 256, 0, stream>>>(outputs, targets, W_dec, b_dec,
                                               tickets, partial, out);
}

// Round 7
// 20.270 us; speedup vs baseline: 5.5591x; 5.5591x over previous
//
#include <hip/hip_runtime.h>
#include <math.h>
#include <float.h>

// Problem constants (fixed by setup_inputs):
//   outputs: [8, 512, 12]            fp32
//   targets: [8, 512, 1, 2, 128]     fp32
//   W_dec:   [12, 256]               fp32
//   b_dec:   [256]                   fp32
//   out:     scalar fp32
#define NCOMP 12
#define NS 128
#define NBS 4096   // 8 * 512

typedef float f32x2 __attribute__((ext_vector_type(2)));

__global__ __launch_bounds__(256)
void p2cp_block_kernel(const float* __restrict__ outputs,
                       const float* __restrict__ targets,
                       const float* __restrict__ W_dec,
                       const float* __restrict__ b_dec,
                       float* __restrict__ partial) {
    const int bsq = blockIdx.x;      // flattened (b, s)
    const int t   = threadIdx.x;     // 0..255

    // cand4[side][m] = {x_{2m}, x_{2m+1}, y_{2m}, y_{2m+1}} (xx/yy each a reg pair)
    // zz[side*128 + i] = |p_i|^2  (pairs {z_{2m}, z_{2m+1}} readable as f32x2)
    __shared__ __align__(16) float4 cand4[2][NS / 2];
    __shared__ __align__(8)  float  zz[2 * NS];
    __shared__ float o[NCOMP];
    __shared__ float red[4];

    if (t < NCOMP) o[t] = outputs[bsq * NCOMP + t];

    // targets per (b,s): [2][128]
    const float* tb = targets + (size_t)bsq * (2 * NS);
    const float tval = tb[t];
    float vx = 0.0f;
    if (t >= NS) vx = tb[t - NS];    // x-coord of v-point t-128
    __syncthreads();   // o[] ready

    float x, y;
    int side, idx;
    if (t < NS) {
        side = 0; idx = t;
        // decode u-point t: x = shapes[t], y = shapes[128+t]
        x = b_dec[t]; y = b_dec[NS + t];
        #pragma unroll
        for (int k = 0; k < NCOMP; ++k) {
            x = fmaf(o[k], W_dec[k * 256 + t], x);
            y = fmaf(o[k], W_dec[k * 256 + NS + t], y);
        }
    } else {
        side = 1; idx = t - NS;
        x = vx; y = tval;            // v-point: x = tb[idx], y = tb[128+idx]
    }
    // scatter into packed pair layout
    float* c4 = reinterpret_cast<float*>(&cand4[side][idx >> 1]);
    c4[(idx & 1)]     = x;           // x slot
    c4[2 + (idx & 1)] = y;           // y slot
    zz[t] = fmaf(x, x, y * y);       // flat slot t == side*128 + idx
    __syncthreads();   // points ready

    // Tiling: group = t>>3 owns 8 points (4 pairs) of its side; groups 0..15 -> u,
    // 16..31 -> v. slice = t&7 handles opposite-side pairs m = slice + 8i.
    const int slice = t & 7;
    const int group = t >> 3;
    const int ownSide = (t < NS) ? 0 : 1;
    const int ownPairBase = (group & 15) * 4;
    const float4* __restrict__ opp4 = cand4[ownSide ^ 1];
    const f32x2*  __restrict__ oppz = reinterpret_cast<const f32x2*>(&zz[(ownSide ^ 1) * NS]);

    // ab[k] = {-2*px, -2*py} for own point k
    f32x2 ab[8];
    float mn[8];
    #pragma unroll
    for (int j = 0; j < 4; ++j) {
        const float4 P = cand4[ownSide][ownPairBase + j];   // {x0,x1,y0,y1}
        f32x2 e0; e0.x = -2.0f * P.x; e0.y = -2.0f * P.z; ab[2 * j]     = e0;
        f32x2 e1; e1.x = -2.0f * P.y; e1.y = -2.0f * P.w; ab[2 * j + 1] = e1;
    }
    #pragma unroll
    for (int k = 0; k < 8; ++k) mn[k] = FLT_MAX;

    // Gram form, packed: dd = { d2'(p, q_{2m}), d2'(p, q_{2m+1}) } - |p|^2
    //   dd = (-2px)*xx + ((-2py)*yy + zz)  via two v_pk_fma_f32
    //   op_sel broadcasts lo (a) or hi (b) half of ab[k] to both lanes.
    #pragma unroll
    for (int i = 0; i < 8; ++i) {
        const int m = slice + 8 * i;
        const float4 q  = opp4[m];    // {x0,x1,y0,y1}: xx = {q.x,q.y}, yy = {q.z,q.w}
        const f32x2 z2 = oppz[m];     // {z0,z1}
        f32x2 xx; xx.x = q.x; xx.y = q.y;
        f32x2 yy; yy.x = q.z; yy.y = q.w;
        #pragma unroll
        for (int k = 0; k < 8; ++k) {
            f32x2 t1, dd;
            asm("v_pk_fma_f32 %0, %1, %2, %3 op_sel:[1,0,0] op_sel_hi:[1,1,1]"
                : "=v"(t1) : "v"(ab[k]), "v"(yy), "v"(z2));   // {b*y0+z0, b*y1+z1}
            asm("v_pk_fma_f32 %0, %1, %2, %3 op_sel:[0,0,0] op_sel_hi:[0,1,1]"
                : "=v"(dd) : "v"(ab[k]), "v"(xx), "v"(t1));   // {a*x0+., a*x1+.}
            asm("v_min3_f32 %0, %1, %2, %3"
                : "=v"(mn[k]) : "v"(mn[k]), "v"(dd.x), "v"(dd.y));
        }
    }

    // Combine partial mins across the 8 slices (adjacent lanes, same wave).
    #pragma unroll
    for (int k = 0; k < 8; ++k) {
        mn[k] = fminf(mn[k], __shfl_xor(mn[k], 1));
        mn[k] = fminf(mn[k], __shfl_xor(mn[k], 2));
        mn[k] = fminf(mn[k], __shfl_xor(mn[k], 4));
    }

    // Lane (group, slice) finalizes its own point #slice -> flat slot t.
    float mm = mn[0];
    #pragma unroll
    for (int k = 1; k < 8; ++k) mm = (slice == k) ? mn[k] : mm;
    const float d2 = fmaxf(mm + zz[t], 0.0f);        // own |p|^2 at flat slot t
    float m = sqrtf(d2 + 1e-12f);                    // sqrt monotone: one sqrt after min

    // Block sum across 256 threads.
    #pragma unroll
    for (int off = 32; off > 0; off >>= 1)
        m += __shfl_down(m, off);
    const int lane = t & 63;
    const int wid  = t >> 6;
    if (lane == 0) red[wid] = m;
    __syncthreads();
    if (t == 0) {
        // per-(b,s): 0.5*(u2v.mean + v2u.mean) = blocksum / 256
        partial[bsq] = red[0] + red[1] + red[2] + red[3];
    }
}

__global__ __launch_bounds__(256)
void final_reduce_kernel(const float* __restrict__ partial,
                         float* __restrict__ out) {
    const int t = threadIdx.x;
    float s = 0.0f;
    #pragma unroll
    for (int i = 0; i < 16; ++i) s += partial[t + 256 * i];
    #pragma unroll
    for (int off = 32; off > 0; off >>= 1)
        s += __shfl_down(s, off);
    __shared__ float red[4];
    const int lane = t & 63;
    const int wid  = t >> 6;
    if (lane == 0) red[wid] = s;
    __syncthreads();
    if (t == 0) {
        float total = red[0] + red[1] + red[2] + red[3];
        out[0] = total * (1.0f / (256.0f * (float)NBS));
    }
}

extern "C" void kernel_launch(void* const* d_in, const int* in_sizes, int n_in,
                              void* d_out, int out_size, void* d_ws, size_t ws_size,
                              hipStream_t stream) {
    const float* outputs = (const float*)d_in[0];
    const float* targets = (const float*)d_in[1];
    const float* W_dec   = (const float*)d_in[2];
    const float* b_dec   = (const float*)d_in[3];
    float* out = (float*)d_out;
    float* ws  = (float*)d_ws;   // 4096 floats = 16 KB of partials

    p2cp_block_kernel<<<NBS, 256, 0, stream>>>(outputs, targets, W_dec, b_dec, ws);
    final_reduce_kernel<<<1, 256, 0, stream>>>(ws, out);
}

// Round 8
// 17.298 us; speedup vs baseline: 6.5140x; 1.1718x over previous
//
#include <hip/hip_runtime.h>
#include <math.h>
#include <float.h>

// Problem constants (fixed by setup_inputs):
//   outputs: [8, 512, 12]  targets: [8, 512, 1, 2, 128]
//   W_dec: [12, 256]       b_dec: [256]      out: scalar fp32
#define NCOMP 12
#define NS 128
#define NBS 4096   // 8 * 512
#define WPB 4      // waves per block (one bsq per wave)

typedef float f32x2 __attribute__((ext_vector_type(2)));
typedef float f32x4 __attribute__((ext_vector_type(4)));

__device__ __forceinline__ f32x4 shfl_xor4(f32x4 v, int mask) {
    f32x4 r;
    r.x = __shfl_xor(v.x, mask);
    r.y = __shfl_xor(v.y, mask);
    r.z = __shfl_xor(v.z, mask);
    r.w = __shfl_xor(v.w, mask);
    return r;
}

__global__ __launch_bounds__(256)
void p2cp_wave_kernel(const float* __restrict__ outputs,
                      const float* __restrict__ targets,
                      const float* __restrict__ W_dec,
                      const float* __restrict__ b_dec,
                      float* __restrict__ partial) {
    const int wav  = threadIdx.x >> 6;            // wave in block: 0..3
    const int lane = threadIdx.x & 63;
    const int bsq  = blockIdx.x * WPB + wav;      // one (b,s) per wave

    // Per-wave LDS: c4[side][pair] = {x0,x1,y0,y1}; zz[side][i] = |p_i|^2.
    // side 0 = u (decoded), side 1 = v (targets).
    __shared__ __align__(16) f32x4 c4s[WPB][2][NS / 2];
    __shared__ __align__(16) float zzs[WPB][2][NS];
    f32x4 (*c4)[NS / 2] = c4s[wav];
    float (*zw)[NS]     = zzs[wav];

    const int half = lane >> 5;   // 0: x-carrier (owns u-points), 1: y-carrier (owns v)
    const int m    = lane & 31;   // carries one coord of points 4m..4m+3

    // ---- o coefficients (12 floats, broadcast within wave) ----
    const float* ob = outputs + (size_t)bsq * NCOMP;      // 48B rows -> 16B aligned
    const f32x4 o0 = *reinterpret_cast<const f32x4*>(ob);
    const f32x4 o1 = *reinterpret_cast<const f32x4*>(ob + 4);
    const f32x4 o2 = *reinterpret_cast<const f32x4*>(ob + 8);

    // ---- decode shape elements e = 4*lane .. 4*lane+3 ----
    // lanes 0..31: x_u of points 4m..4m+3; lanes 32..63: y_u of points 4m..4m+3
    f32x4 du = *reinterpret_cast<const f32x4*>(b_dec + 4 * lane);
    const float* wb = W_dec + 4 * lane;
    #pragma unroll
    for (int k = 0; k < 4; ++k)
        du += o0[k] * *reinterpret_cast<const f32x4*>(wb + (k    ) * 256);
    #pragma unroll
    for (int k = 0; k < 4; ++k)
        du += o1[k] * *reinterpret_cast<const f32x4*>(wb + (k + 4) * 256);
    #pragma unroll
    for (int k = 0; k < 4; ++k)
        du += o2[k] * *reinterpret_cast<const f32x4*>(wb + (k + 8) * 256);

    // ---- target coords, same split: lanes<32 x_v, lanes>=32 y_v ----
    const float* tb = targets + (size_t)bsq * (2 * NS);
    const f32x4 dv = *reinterpret_cast<const f32x4*>(tb + 4 * lane);

    // ---- partner exchange: complete own points in registers ----
    const f32x4 pu = shfl_xor4(du, 32);
    const f32x4 pv = shfl_xor4(dv, 32);
    // x-lane: own u-points, x = du, y = pu.   y-lane: own v-points, x = pv, y = dv.
    const f32x4 ox = half ? pv : du;
    const f32x4 oy = half ? dv : pu;
    f32x4 zz4;
    #pragma unroll
    for (int c = 0; c < 4; ++c) zz4[c] = fmaf(ox[c], ox[c], oy[c] * oy[c]);

    // ---- pack candidates to LDS ----
    // u-side: every lane writes its du (x-half at +0, y-half at +8); v-side: dv.
    {
        float* u0 = reinterpret_cast<float*>(&c4[0][2 * m])     + 2 * half;
        float* u1 = reinterpret_cast<float*>(&c4[0][2 * m + 1]) + 2 * half;
        float* v0 = reinterpret_cast<float*>(&c4[1][2 * m])     + 2 * half;
        float* v1 = reinterpret_cast<float*>(&c4[1][2 * m + 1]) + 2 * half;
        *reinterpret_cast<f32x2*>(u0) = f32x2{du.x, du.y};
        *reinterpret_cast<f32x2*>(u1) = f32x2{du.z, du.w};
        *reinterpret_cast<f32x2*>(v0) = f32x2{dv.x, dv.y};
        *reinterpret_cast<f32x2*>(v1) = f32x2{dv.z, dv.w};
        *reinterpret_cast<f32x4*>(&zw[half][4 * m]) = zz4;  // x-lanes: zz_u, y-lanes: zz_v
    }
    // Wave-synchronous: one LDS drain, NO barrier.
    asm volatile("s_waitcnt lgkmcnt(0)" ::: "memory");
    __builtin_amdgcn_sched_barrier(0);

    // ---- main scan: own 4 points vs all 64 opposite-side pairs ----
    const f32x4* cp = c4[1 - half];
    const float* zp = zw[1 - half];

    f32x2 ab[4];
    float mn[4];
    #pragma unroll
    for (int k = 0; k < 4; ++k) {
        ab[k] = f32x2{-2.0f * ox[k], -2.0f * oy[k]};
        mn[k] = FLT_MAX;
    }

    #pragma unroll 8
    for (int i = 0; i < NS / 2; ++i) {
        const f32x4 q  = cp[i];                                   // {x0,x1,y0,y1} broadcast
        const f32x2 z2 = *reinterpret_cast<const f32x2*>(zp + 2 * i);
        f32x2 xx; xx.x = q.x; xx.y = q.y;
        f32x2 yy; yy.x = q.z; yy.y = q.w;
        #pragma unroll
        for (int k = 0; k < 4; ++k) {
            f32x2 t1, dd;
            asm("v_pk_fma_f32 %0, %1, %2, %3 op_sel:[1,0,0] op_sel_hi:[1,1,1]"
                : "=v"(t1) : "v"(ab[k]), "v"(yy), "v"(z2));   // {b*y0+z0, b*y1+z1}
            asm("v_pk_fma_f32 %0, %1, %2, %3 op_sel:[0,0,0] op_sel_hi:[0,1,1]"
                : "=v"(dd) : "v"(ab[k]), "v"(xx), "v"(t1));   // {a*x0+., a*x1+.}
            asm("v_min3_f32 %0, %1, %2, %3"
                : "=v"(mn[k]) : "v"(mn[k]), "v"(dd.x), "v"(dd.y));
        }
    }

    // ---- finalize own 4 points, wave-sum, store ----
    float s = 0.0f;
    #pragma unroll
    for (int k = 0; k < 4; ++k) {
        const float d2 = fmaxf(mn[k] + zz4[k], 0.0f);  // matches jnp.maximum(d2,0)
        s += sqrtf(d2 + 1e-12f);                       // sqrt monotone: sqrt after min
    }
    #pragma unroll
    for (int off = 32; off > 0; off >>= 1)
        s += __shfl_xor(s, off);
    if (lane == 0)
        partial[bsq] = s;   // sum of 256 per-point min-distances for this (b,s)
}

__global__ __launch_bounds__(256)
void final_reduce_kernel(const float* __restrict__ partial,
                         float* __restrict__ out) {
    const int t = threadIdx.x;
    float s = 0.0f;
    #pragma unroll
    for (int i = 0; i < 16; ++i) s += partial[t + 256 * i];
    #pragma unroll
    for (int off = 32; off > 0; off >>= 1)
        s += __shfl_down(s, off);
    __shared__ float red[4];
    const int lane = t & 63;
    const int wid  = t >> 6;
    if (lane == 0) red[wid] = s;
    __syncthreads();
    if (t == 0) {
        const float total = red[0] + red[1] + red[2] + red[3];
        // per-(b,s): 0.5*(u2v.mean+v2u.mean) = wavesum/256; then mean over 4096
        out[0] = total * (1.0f / (256.0f * (float)NBS));
    }
}

extern "C" void kernel_launch(void* const* d_in, const int* in_sizes, int n_in,
                              void* d_out, int out_size, void* d_ws, size_t ws_size,
                              hipStream_t stream) {
    const float* outputs = (const float*)d_in[0];
    const float* targets = (const float*)d_in[1];
    const float* W_dec   = (const float*)d_in[2];
    const float* b_dec   = (const float*)d_in[3];
    float* out = (float*)d_out;
    float* ws  = (float*)d_ws;   // 4096 floats = 16 KB of partials

    p2cp_wave_kernel<<<NBS / WPB, 256, 0, stream>>>(outputs, targets, W_dec, b_dec, ws);
    final_reduce_kernel<<<1, 256, 0, stream>>>(ws, out);
}